// Round 12
// baseline (428.557 us; speedup 1.0000x reference)
//
#include <hip/hip_runtime.h>
#include <math.h>

#define SCALE 0.036084391824351613f /* 1/sqrt(768) */

typedef unsigned short us;
typedef __attribute__((ext_vector_type(8))) short short8;
typedef __attribute__((ext_vector_type(4))) short short4s;
typedef __attribute__((ext_vector_type(4))) float f32x4;
#define MFMA16(a, b, c) __builtin_amdgcn_mfma_f32_16x16x32_bf16(a, b, c, 0, 0, 0)

__device__ __forceinline__ us f2bf(float f) {
  unsigned u = __float_as_uint(f);
  unsigned r = (u + 0x7fffu + ((u >> 16) & 1u)) >> 16;
  return (us)r;
}
__device__ __forceinline__ float bf2f(us u) { return __uint_as_float(((unsigned)u) << 16); }

__device__ __forceinline__ void split8(f32x4 a, f32x4 b, short8& hi, short8& lo) {
  float x[8] = {a[0], a[1], a[2], a[3], b[0], b[1], b[2], b[3]};
#pragma unroll
  for (int i = 0; i < 8; i++) {
    us h = f2bf(x[i]);
    hi[i] = (short)h;
    lo[i] = (short)f2bf(x[i] - bf2f(h));
  }
}

// ---------------- reduction helpers (blockDim = 256) ----------------
__device__ __forceinline__ float blockReduceSum(float v, float* sh) {
#pragma unroll
  for (int o = 32; o > 0; o >>= 1) v += __shfl_xor(v, o, 64);
  int lane = threadIdx.x & 63, wid = threadIdx.x >> 6;
  __syncthreads();
  if (lane == 0) sh[wid] = v;
  __syncthreads();
  float r = sh[0];
  int nw = blockDim.x >> 6;
  for (int i = 1; i < nw; i++) r += sh[i];
  return r;
}

__device__ __forceinline__ float gelu_exact(float x) {
  return 0.5f * x * (1.0f + erff(x * 0.7071067811865476f));
}

// ---------------- K2: queries prep -> qgh/qgl (bf16 hi/lo), s1, qb, bqn, gcons ----
__global__ void __launch_bounds__(256) k_prep_queries(
    const float* __restrict__ bq, const float* __restrict__ qn_g, const float* __restrict__ qn_b,
    const float* __restrict__ tn_g, const float* __restrict__ tn_b,
    us* __restrict__ qgh, us* __restrict__ qgl,
    float* __restrict__ s1, float* __restrict__ qb,
    float* __restrict__ bqn, float* __restrict__ gcons) {
  __shared__ float sh[8];
  int k = blockIdx.x, t = threadIdx.x;
  const float* xr = bq + (size_t)k * 768;
  float x0 = xr[t], x1 = xr[t + 256], x2 = xr[t + 512];
  float sx = blockReduceSum(x0 + x1 + x2, sh);
  float sxx = blockReduceSum(x0 * x0 + x1 * x1 + x2 * x2, sh);
  float mean = sx * (1.0f / 768.0f);
  float var = fmaxf(sxx * (1.0f / 768.0f) - mean * mean, 0.0f);
  float rs = rsqrtf(var + 1e-5f);
  float y0 = (x0 - mean) * rs * qn_g[t] + qn_b[t];
  float y1 = (x1 - mean) * rs * qn_g[t + 256] + qn_b[t + 256];
  float y2 = (x2 - mean) * rs * qn_g[t + 512] + qn_b[t + 512];
  float ss = blockReduceSum(y0 * y0 + y1 * y1 + y2 * y2, sh);
  float inv = 1.0f / fmaxf(sqrtf(ss), 1e-12f);
  float q0 = y0 * inv, q1 = y1 * inv, q2 = y2 * inv;
  float tg0 = tn_g[t], tg1 = tn_g[t + 256], tg2 = tn_g[t + 512];
  float tb0 = tn_b[t], tb1 = tn_b[t + 256], tb2 = tn_b[t + 512];
  float g0 = q0 * tg0, g1 = q1 * tg1, g2 = q2 * tg2;
  us h0 = f2bf(g0), h1 = f2bf(g1), h2 = f2bf(g2);
  qgh[(size_t)k * 768 + t] = h0;
  qgh[(size_t)k * 768 + t + 256] = h1;
  qgh[(size_t)k * 768 + t + 512] = h2;
  qgl[(size_t)k * 768 + t] = f2bf(g0 - bf2f(h0));
  qgl[(size_t)k * 768 + t + 256] = f2bf(g1 - bf2f(h1));
  qgl[(size_t)k * 768 + t + 512] = f2bf(g2 - bf2f(h2));
  float s1p = blockReduceSum(g0 + g1 + g2, sh);
  float qbp = blockReduceSum(q0 * tb0 + q1 * tb1 + q2 * tb2, sh);
  if (t == 0) { s1[k] = s1p; qb[k] = qbp; }
  float inv2 = 1.0f / fmaxf(sqrtf(sxx), 1e-12f);
  bqn[(size_t)k * 768 + t] = x0 * inv2;
  bqn[(size_t)k * 768 + t + 256] = x1 * inv2;
  bqn[(size_t)k * 768 + t + 512] = x2 * inv2;
  float sggp = blockReduceSum(tg0 * tg0 + tg1 * tg1 + tg2 * tg2, sh);
  float sgbp = blockReduceSum(tg0 * tb0 + tg1 * tb1 + tg2 * tb2, sh);
  float sbbp = blockReduceSum(tb0 * tb0 + tb1 * tb1 + tb2 * tb2, sh);
  if (k == 0 && t == 0) { gcons[0] = sggp; gcons[1] = sgbp; gcons[2] = sbbp; }
}

// ---------------- K3: gram row-k squared error partials ----------------
__global__ void __launch_bounds__(256) k_gram(const float* __restrict__ bqn,
                                              float* __restrict__ gpart) {
  __shared__ float bk[768];
  __shared__ float arr[64];
  int k = blockIdx.x, t = threadIdx.x;
  bk[t] = bqn[(size_t)k * 768 + t];
  bk[t + 256] = bqn[(size_t)k * 768 + t + 256];
  bk[t + 512] = bqn[(size_t)k * 768 + t + 512];
  __syncthreads();
  int j = t >> 2, sub = t & 3;
  const float* bj = bqn + (size_t)j * 768 + sub * 192;
  float v = 0.0f;
  for (int d = 0; d < 192; d++) v += bk[sub * 192 + d] * bj[d];
  v += __shfl_xor(v, 1, 64);
  v += __shfl_xor(v, 2, 64);
  if (sub == 0) { float e = v - (j == k ? 1.0f : 0.0f); arr[j] = e * e; }
  __syncthreads();
  if (t < 64) {
    float s = arr[t];
#pragma unroll
    for (int o = 32; o > 0; o >>= 1) s += __shfl_xor(s, o, 64);
    if (t == 0) gpart[k] = s;
  }
}

// ---------------- K4: transpose+split rw1 [768,3072] -> w1th/w1tl [3072,768] -----
__global__ void __launch_bounds__(256) k_w1t(const float* __restrict__ rw1,
                                             us* __restrict__ w1th, us* __restrict__ w1tl) {
  __shared__ float tl[32][33];
  int d0 = blockIdx.x * 32, h0 = blockIdx.y * 32;
  int t = threadIdx.x, tx = t & 31, ty = t >> 5;
#pragma unroll
  for (int j = 0; j < 4; j++)
    tl[ty + j * 8][tx] = rw1[(size_t)(d0 + ty + j * 8) * 3072 + h0 + tx];
  __syncthreads();
#pragma unroll
  for (int j = 0; j < 4; j++) {
    float v = tl[tx][ty + j * 8];
    us h = f2bf(v);
    w1th[(size_t)(h0 + ty + j * 8) * 768 + d0 + tx] = h;
    w1tl[(size_t)(h0 + ty + j * 8) * 768 + d0 + tx] = f2bf(v - bf2f(h));
  }
}

// ---------------- K5: attn logits GEMM + fused LN/L2 stats + rowsum(exp) --------
__global__ void __launch_bounds__(256) k_attn_mfma(
    const float* __restrict__ x, const us* __restrict__ qgh, const us* __restrict__ qgl,
    const float* __restrict__ s1v, const float* __restrict__ qbv,
    const float* __restrict__ tng, const float* __restrict__ tnb,
    const float* __restrict__ gcons, float* __restrict__ L, float* __restrict__ rowsum) {
  __shared__ __align__(16) us qsh[64 * 32], qsl[64 * 32];
  __shared__ __align__(16) us xsh[128 * 32], xsl[128 * 32];
  __shared__ float sA[128], sB[128], sC[128];
  __shared__ float sRow[4][64];
  const int b = blockIdx.y, n0 = blockIdx.x * 128;
  const int t = threadIdx.x, w = t >> 6, l = t & 63;
  const int sr = t >> 2, sq = t & 3;
  const us* qsrcH = qgh + (size_t)sr * 768 + sq * 8;
  const us* qsrcL = qgl + (size_t)sr * 768 + sq * 8;
  const float* xsrc = x + ((size_t)b * 4096 + n0 + sr) * 768 + sq * 8;
  f32x4 acc[4][2];
#pragma unroll
  for (int i = 0; i < 4; i++)
#pragma unroll
    for (int j = 0; j < 2; j++) acc[i][j] = (f32x4){0.f, 0.f, 0.f, 0.f};
  float s0x = 0, s0xx = 0, s0a = 0, s0b = 0, s0c = 0;
  float t1x = 0, t1xx = 0, t1a = 0, t1b = 0, t1c = 0;
  short8 qh = *(const short8*)qsrcH, ql = *(const short8*)qsrcL;
  f32x4 x0a = *(const f32x4*)xsrc, x0b = *(const f32x4*)(xsrc + 4);
  f32x4 x1a = *(const f32x4*)(xsrc + (size_t)64 * 768);
  f32x4 x1b = *(const f32x4*)(xsrc + (size_t)64 * 768 + 4);
  for (int dk = 0; dk < 768; dk += 32) {
    f32x4 ga = *(const f32x4*)(tng + dk + sq * 8);
    f32x4 gA = *(const f32x4*)(tng + dk + sq * 8 + 4);
    f32x4 ba = *(const f32x4*)(tnb + dk + sq * 8);
    f32x4 bA = *(const f32x4*)(tnb + dk + sq * 8 + 4);
#pragma unroll
    for (int i = 0; i < 4; i++) {
      float g1 = ga[i], g2 = gA[i], b1 = ba[i], b2 = bA[i];
      float xv = x0a[i]; float gx = g1 * xv;
      s0x += xv; s0xx = fmaf(xv, xv, s0xx);
      s0a = fmaf(gx, gx, s0a); s0b = fmaf(g1, gx, s0b); s0c = fmaf(b1, gx, s0c);
      xv = x0b[i]; gx = g2 * xv;
      s0x += xv; s0xx = fmaf(xv, xv, s0xx);
      s0a = fmaf(gx, gx, s0a); s0b = fmaf(g2, gx, s0b); s0c = fmaf(b2, gx, s0c);
      xv = x1a[i]; gx = g1 * xv;
      t1x += xv; t1xx = fmaf(xv, xv, t1xx);
      t1a = fmaf(gx, gx, t1a); t1b = fmaf(g1, gx, t1b); t1c = fmaf(b1, gx, t1c);
      xv = x1b[i]; gx = g2 * xv;
      t1x += xv; t1xx = fmaf(xv, xv, t1xx);
      t1a = fmaf(gx, gx, t1a); t1b = fmaf(g2, gx, t1b); t1c = fmaf(b2, gx, t1c);
    }
    short8 hi, lo;
    __syncthreads();
    *(short8*)&qsh[sr * 32 + sq * 8] = qh; *(short8*)&qsl[sr * 32 + sq * 8] = ql;
    split8(x0a, x0b, hi, lo);
    *(short8*)&xsh[sr * 32 + sq * 8] = hi; *(short8*)&xsl[sr * 32 + sq * 8] = lo;
    split8(x1a, x1b, hi, lo);
    *(short8*)&xsh[(sr + 64) * 32 + sq * 8] = hi; *(short8*)&xsl[(sr + 64) * 32 + sq * 8] = lo;
    __syncthreads();
    if (dk + 32 < 768) {
      int d2 = dk + 32;
      qh = *(const short8*)(qsrcH + d2); ql = *(const short8*)(qsrcL + d2);
      x0a = *(const f32x4*)(xsrc + d2); x0b = *(const f32x4*)(xsrc + d2 + 4);
      x1a = *(const f32x4*)(xsrc + (size_t)64 * 768 + d2);
      x1b = *(const f32x4*)(xsrc + (size_t)64 * 768 + d2 + 4);
    }
    short8 ah[4], al[4];
#pragma unroll
    for (int kt = 0; kt < 4; kt++) {
      int off = (kt * 16 + (l & 15)) * 32 + (l >> 4) * 8;
      ah[kt] = *(const short8*)&qsh[off];
      al[kt] = *(const short8*)&qsl[off];
    }
#pragma unroll
    for (int nt = 0; nt < 2; nt++) {
      int off = (w * 32 + nt * 16 + (l & 15)) * 32 + (l >> 4) * 8;
      short8 bh = *(const short8*)&xsh[off];
      short8 bl = *(const short8*)&xsl[off];
#pragma unroll
      for (int kt = 0; kt < 4; kt++) {
        acc[kt][nt] = MFMA16(ah[kt], bh, acc[kt][nt]);
        acc[kt][nt] = MFMA16(ah[kt], bl, acc[kt][nt]);
        acc[kt][nt] = MFMA16(al[kt], bh, acc[kt][nt]);
        acc[kt][nt] = MFMA16(al[kt], bl, acc[kt][nt]);
      }
    }
  }
  float sgg = gcons[0], sgb = gcons[1], sbb = gcons[2];
#define R4(v) v += __shfl_xor(v, 1, 64); v += __shfl_xor(v, 2, 64)
  R4(s0x); R4(s0xx); R4(s0a); R4(s0b); R4(s0c);
  R4(t1x); R4(t1xx); R4(t1a); R4(t1b); R4(t1c);
#undef R4
  if (sq == 0) {
    {
      float m = s0x * (1.0f / 768.0f);
      float var = fmaxf(s0xx * (1.0f / 768.0f) - m * m, 0.0f);
      float rs = rsqrtf(var + 1e-5f);
      float ss = fmaxf(rs * rs * (s0a - 2.0f * m * s0b + m * m * sgg) +
                       2.0f * rs * (s0c - m * sgb) + sbb, 0.0f);
      float inv = 1.0f / fmaxf(sqrtf(ss), 1e-12f);
      float A = SCALE * inv * rs;
      sA[sr] = A; sB[sr] = A * m; sC[sr] = SCALE * inv;
    }
    {
      float m = t1x * (1.0f / 768.0f);
      float var = fmaxf(t1xx * (1.0f / 768.0f) - m * m, 0.0f);
      float rs = rsqrtf(var + 1e-5f);
      float ss = fmaxf(rs * rs * (t1a - 2.0f * m * t1b + m * m * sgg) +
                       2.0f * rs * (t1c - m * sgb) + sbb, 0.0f);
      float inv = 1.0f / fmaxf(sqrtf(ss), 1e-12f);
      float A = SCALE * inv * rs;
      sA[sr + 64] = A; sB[sr + 64] = A * m; sC[sr + 64] = SCALE * inv;
    }
  }
  __syncthreads();
  // |logit| <= SCALE, so exp without max-subtraction is safe.
  float esum[4][4];
#pragma unroll
  for (int kt = 0; kt < 4; kt++)
#pragma unroll
    for (int r = 0; r < 4; r++) esum[kt][r] = 0.f;
#pragma unroll
  for (int nt = 0; nt < 2; nt++) {
    int nn = w * 32 + nt * 16 + (l & 15);
    int n = n0 + nn;
    float Av = sA[nn], Bv = sB[nn], Cv = sC[nn];
#pragma unroll
    for (int kt = 0; kt < 4; kt++) {
#pragma unroll
      for (int r = 0; r < 4; r++) {
        int k = kt * 16 + (l >> 4) * 4 + r;
        float v = Av * acc[kt][nt][r] - Bv * s1v[k] + Cv * qbv[k];
        L[((size_t)b * 64 + k) * 4096 + n] = v;
        esum[kt][r] += expf(v);
      }
    }
  }
#pragma unroll
  for (int kt = 0; kt < 4; kt++)
#pragma unroll
    for (int r = 0; r < 4; r++) {
      float e = esum[kt][r];
      e += __shfl_xor(e, 1, 64);
      e += __shfl_xor(e, 2, 64);
      e += __shfl_xor(e, 4, 64);
      e += __shfl_xor(e, 8, 64);
      if ((l & 15) == 0) sRow[w][kt * 16 + (l >> 4) * 4 + r] = e;
    }
  __syncthreads();
  if (t < 64)
    atomicAdd(&rowsum[b * 64 + t], sRow[0][t] + sRow[1][t] + sRow[2][t] + sRow[3][t]);
}

// ---------------- K7: zero bs + scores + rowsum (contiguous) ----------------
__global__ void __launch_bounds__(256) k_zero(float* __restrict__ p) {
  ((f32x4*)p)[blockIdx.x * 256 + threadIdx.x] = (f32x4){0.f, 0.f, 0.f, 0.f};
}

// ---------------- K8: basis_states GEMM (d=128, z=8); softmax in staging --------
// x-tile LDS uses XOR swizzle (byte ^= ((row>>3)&3)<<5) to kill the 4-way bank
// conflict on the column-gather reads (write & read use the same involution).
__global__ void __launch_bounds__(256) k_pv_mfma(
    const float* __restrict__ x, const float* __restrict__ W,
    const float* __restrict__ rowsum, float* __restrict__ S) {
  __shared__ __align__(16) us wth[64 * 32], wtl[64 * 32];
  __shared__ __align__(16) us xth[8 * 32 * 16], xtl[8 * 32 * 16];
  const int b = blockIdx.y, d0 = blockIdx.x * 128, nb = blockIdx.z * 512;
  const int t = threadIdx.x, w = t >> 6, l = t & 63;
  const int krow = t >> 2;
  const float* wsrc = W + ((size_t)b * 64 + krow) * 4096 + nb + (t & 3) * 8;
  const float ir = 1.0f / rowsum[b * 64 + krow];
  const int gg = t >> 6, nn = (t >> 1) & 31, hh = t & 1;
  const float* xsrc0 = x + ((size_t)b * 4096 + nb + nn) * 768 + d0 + gg * 16 + hh * 8;
  const float* xsrc1 = xsrc0 + 64;  // groups 4..7
  // swizzled staging offsets (us index within group tile of 512 us)
  const int wbyte = (nn * 32 + hh * 16) ^ (((nn >> 3) & 3) << 5);
  const int woff0 = gg * 512 + (wbyte >> 1);
  const int woff1 = (gg + 4) * 512 + (wbyte >> 1);
  f32x4 acc[4][2];
#pragma unroll
  for (int i = 0; i < 4; i++)
#pragma unroll
    for (int j = 0; j < 2; j++) acc[i][j] = (f32x4){0.f, 0.f, 0.f, 0.f};
  f32x4 w0a = *(const f32x4*)wsrc, w0b = *(const f32x4*)(wsrc + 4);
  f32x4 xa0 = *(const f32x4*)xsrc0, xb0 = *(const f32x4*)(xsrc0 + 4);
  f32x4 xa1 = *(const f32x4*)xsrc1, xb1 = *(const f32x4*)(xsrc1 + 4);
  for (int ns = 0; ns < 512; ns += 32) {
    short8 hi, lo;
    f32x4 e0, e1;
#pragma unroll
    for (int i = 0; i < 4; i++) {
      e0[i] = expf(w0a[i]) * ir;
      e1[i] = expf(w0b[i]) * ir;
    }
    __syncthreads();
    split8(e0, e1, hi, lo);
    *(short8*)&wth[krow * 32 + (t & 3) * 8] = hi;
    *(short8*)&wtl[krow * 32 + (t & 3) * 8] = lo;
    split8(xa0, xb0, hi, lo);
    *(short8*)&xth[woff0] = hi; *(short8*)&xtl[woff0] = lo;
    split8(xa1, xb1, hi, lo);
    *(short8*)&xth[woff1] = hi; *(short8*)&xtl[woff1] = lo;
    __syncthreads();
    if (ns + 32 < 512) {
      w0a = *(const f32x4*)(wsrc + ns + 32); w0b = *(const f32x4*)(wsrc + ns + 36);
      const float* p0 = xsrc0 + (size_t)(ns + 32) * 768;
      xa0 = *(const f32x4*)p0; xb0 = *(const f32x4*)(p0 + 4);
      xa1 = *(const f32x4*)(p0 + 64); xb1 = *(const f32x4*)(p0 + 68);
    }
    short8 ah[4], al[4];
#pragma unroll
    for (int kt = 0; kt < 4; kt++) {
      int off = (kt * 16 + (l & 15)) * 32 + (l >> 4) * 8;
      ah[kt] = *(const short8*)&wth[off];
      al[kt] = *(const short8*)&wtl[off];
    }
    const int rb = (l >> 4) * 8, cc2 = (l & 15) * 2;
#pragma unroll
    for (int dt = 0; dt < 2; dt++) {
      const int grp = (2 * w + dt) * 512;
      short8 bh, bl;
#pragma unroll
      for (int i = 0; i < 8; i++) {
        int row = rb + i;
        int boff = (row * 32 + cc2) ^ (((row >> 3) & 3) << 5);
        int idx = grp + (boff >> 1);
        bh[i] = (short)xth[idx];
        bl[i] = (short)xtl[idx];
      }
#pragma unroll
      for (int kt = 0; kt < 4; kt++) {
        acc[kt][dt] = MFMA16(ah[kt], bh, acc[kt][dt]);
        acc[kt][dt] = MFMA16(ah[kt], bl, acc[kt][dt]);
        acc[kt][dt] = MFMA16(al[kt], bh, acc[kt][dt]);
        acc[kt][dt] = MFMA16(al[kt], bl, acc[kt][dt]);
      }
    }
  }
#pragma unroll
  for (int dt = 0; dt < 2; dt++) {
    int d = d0 + w * 32 + dt * 16 + (l & 15);
#pragma unroll
    for (int kt = 0; kt < 4; kt++) {
#pragma unroll
      for (int r = 0; r < 4; r++) {
        int k = kt * 16 + (l >> 4) * 4 + r;
        atomicAdd(&S[((size_t)b * 64 + k) * 768 + d], acc[kt][dt][r]);
      }
    }
  }
}

// ---------------- K9: LN over 768 rows -> bf16 hi/lo out (wave-per-row) ---------
__global__ void __launch_bounds__(256) k_ln768(
    const float* __restrict__ in, const float* __restrict__ g, const float* __restrict__ b,
    us* __restrict__ outh, us* __restrict__ outl) {
  int wid = threadIdx.x >> 6, lane = threadIdx.x & 63;
  size_t row = (size_t)blockIdx.x * 4 + wid;
  const f32x4* xr = (const f32x4*)(in + row * 768);
  f32x4 v[3];
  float sx = 0, sxx = 0;
#pragma unroll
  for (int j = 0; j < 3; j++) {
    v[j] = xr[lane + j * 64];
#pragma unroll
    for (int i = 0; i < 4; i++) { sx += v[j][i]; sxx = fmaf(v[j][i], v[j][i], sxx); }
  }
#pragma unroll
  for (int o = 32; o > 0; o >>= 1) { sx += __shfl_xor(sx, o, 64); sxx += __shfl_xor(sxx, o, 64); }
  float mean = sx * (1.0f / 768.0f);
  float var = fmaxf(sxx * (1.0f / 768.0f) - mean * mean, 0.0f);
  float rs = rsqrtf(var + 1e-5f);
  const f32x4* gp = (const f32x4*)g;
  const f32x4* bp = (const f32x4*)b;
#pragma unroll
  for (int j = 0; j < 3; j++) {
    f32x4 gv = gp[lane + j * 64], bv = bp[lane + j * 64];
    short4s h4, l4;
#pragma unroll
    for (int i = 0; i < 4; i++) {
      float y = (v[j][i] - mean) * rs * gv[i] + bv[i];
      us h = f2bf(y);
      h4[i] = (short)h;
      l4[i] = (short)f2bf(y - bf2f(h));
    }
    int e = (lane + j * 64) * 4;
    *(short4s*)&outh[row * 768 + e] = h4;
    *(short4s*)&outl[row * 768 + e] = l4;
  }
}

// ---------------- K10: routing-MLP GEMM 128x128, 512 thr, fused score dot -------
__global__ void __launch_bounds__(512) k_rh_mfma(
    const us* __restrict__ rhh, const us* __restrict__ rhl,
    const us* __restrict__ w1th, const us* __restrict__ w1tl,
    const float* __restrict__ rb1, const float* __restrict__ rw2,
    float* __restrict__ scores_raw) {
  __shared__ __align__(16) us ash[128 * 32], asl[128 * 32];
  __shared__ __align__(16) us bsh[128 * 32], bsl[128 * 32];
  __shared__ float spart[4][128];
  const int h0 = blockIdx.x * 128, m0 = blockIdx.y * 128;
  const int t = threadIdx.x, w = t >> 6, l = t & 63;
  const int wm = w >> 2, wh = w & 3;
  const int sr = t >> 2, sq = t & 3;
  const us* aH = rhh + (size_t)(m0 + sr) * 768 + sq * 8;
  const us* aL = rhl + (size_t)(m0 + sr) * 768 + sq * 8;
  const us* bH = w1th + (size_t)(h0 + sr) * 768 + sq * 8;
  const us* bL = w1tl + (size_t)(h0 + sr) * 768 + sq * 8;
  f32x4 acc[4][2];
#pragma unroll
  for (int i = 0; i < 4; i++)
#pragma unroll
    for (int j = 0; j < 2; j++) acc[i][j] = (f32x4){0.f, 0.f, 0.f, 0.f};
  short8 a0h = *(const short8*)aH, a0l = *(const short8*)aL;
  short8 b0h = *(const short8*)bH, b0l = *(const short8*)bL;
  for (int dk = 0; dk < 768; dk += 32) {
    __syncthreads();
    *(short8*)&ash[sr * 32 + sq * 8] = a0h; *(short8*)&asl[sr * 32 + sq * 8] = a0l;
    *(short8*)&bsh[sr * 32 + sq * 8] = b0h; *(short8*)&bsl[sr * 32 + sq * 8] = b0l;
    __syncthreads();
    if (dk + 32 < 768) {
      int d2 = dk + 32;
      a0h = *(const short8*)(aH + d2); a0l = *(const short8*)(aL + d2);
      b0h = *(const short8*)(bH + d2); b0l = *(const short8*)(bL + d2);
    }
    short8 ah[4], al[4];
#pragma unroll
    for (int kt = 0; kt < 4; kt++) {
      int off = ((wm * 64 + kt * 16 + (l & 15))) * 32 + (l >> 4) * 8;
      ah[kt] = *(const short8*)&ash[off];
      al[kt] = *(const short8*)&asl[off];
    }
#pragma unroll
    for (int nt = 0; nt < 2; nt++) {
      int off = ((wh * 32 + nt * 16 + (l & 15))) * 32 + (l >> 4) * 8;
      short8 bh = *(const short8*)&bsh[off];
      short8 bl = *(const short8*)&bsl[off];
#pragma unroll
      for (int kt = 0; kt < 4; kt++) {
        acc[kt][nt] = MFMA16(ah[kt], bh, acc[kt][nt]);
        acc[kt][nt] = MFMA16(ah[kt], bl, acc[kt][nt]);
        acc[kt][nt] = MFMA16(al[kt], bh, acc[kt][nt]);
        acc[kt][nt] = MFMA16(al[kt], bl, acc[kt][nt]);
      }
    }
  }
  float psum[4][4];
#pragma unroll
  for (int kt = 0; kt < 4; kt++)
#pragma unroll
    for (int r = 0; r < 4; r++) psum[kt][r] = 0.f;
#pragma unroll
  for (int nt = 0; nt < 2; nt++) {
    int h = h0 + wh * 32 + nt * 16 + (l & 15);
    float bias = rb1[h];
    float rw2v = rw2[h];
#pragma unroll
    for (int kt = 0; kt < 4; kt++) {
#pragma unroll
      for (int r = 0; r < 4; r++) {
        float g = gelu_exact(acc[kt][nt][r] + bias);
        psum[kt][r] = fmaf(g, rw2v, psum[kt][r]);
      }
    }
  }
#pragma unroll
  for (int kt = 0; kt < 4; kt++)
#pragma unroll
    for (int r = 0; r < 4; r++) {
      float v = psum[kt][r];
      v += __shfl_xor(v, 1, 64);
      v += __shfl_xor(v, 2, 64);
      v += __shfl_xor(v, 4, 64);
      v += __shfl_xor(v, 8, 64);
      if ((l & 15) == 0) spart[wh][wm * 64 + kt * 16 + (l >> 4) * 4 + r] = v;
    }
  __syncthreads();
  if (t < 128)
    atomicAdd(&scores_raw[m0 + t], spart[0][t] + spart[1][t] + spart[2][t] + spart[3][t]);
}

// ---------------- K13: topk + basis_summary + both LNs -> fused [32,1536] --------
__global__ void __launch_bounds__(256) k_fused(
    const float* __restrict__ bs, const float* __restrict__ scores_raw,
    const float* __restrict__ rb2, const float* __restrict__ gf,
    const float* __restrict__ bn_g, const float* __restrict__ bn_b,
    const float* __restrict__ gn_g, const float* __restrict__ gn_b,
    float* __restrict__ fused, float* __restrict__ rw_out) {
  __shared__ float sh[8];
  __shared__ float wsh[64];
  int b = blockIdx.x, t = threadIdx.x;
  if (t < 64) {
    float z = scores_raw[b * 64 + t] + rb2[0];
    float s = fmaxf(z, 0.0f) + log1pf(expf(-fabsf(z)));
    bool sel = false;
    for (int it = 0; it < 8; it++) {
      float v = sel ? -INFINITY : s;
      int idx = t;
#pragma unroll
      for (int o = 32; o > 0; o >>= 1) {
        float v2 = __shfl_xor(v, o, 64);
        int i2 = __shfl_xor(idx, o, 64);
        if (v2 > v || (v2 == v && i2 < idx)) { v = v2; idx = i2; }
      }
      if (t == idx) sel = true;
    }
    float wv = sel ? s : 0.0f;
    float tot = wv;
#pragma unroll
    for (int o = 32; o > 0; o >>= 1) tot += __shfl_xor(tot, o, 64);
    float wt = wv / fmaxf(tot, 1e-8f);
    wsh[t] = wt;
    rw_out[b * 64 + t] = wt;
  }
  __syncthreads();
  float v0 = 0, v1 = 0, v2 = 0;
  const float* bsb = bs + (size_t)b * 64 * 768;
  for (int k = 0; k < 64; k++) {
    float w = wsh[k];
    if (w != 0.0f) {
      v0 = fmaf(w, bsb[(size_t)k * 768 + t], v0);
      v1 = fmaf(w, bsb[(size_t)k * 768 + t + 256], v1);
      v2 = fmaf(w, bsb[(size_t)k * 768 + t + 512], v2);
    }
  }
  float sx = blockReduceSum(v0 + v1 + v2, sh);
  float sxx = blockReduceSum(v0 * v0 + v1 * v1 + v2 * v2, sh);
  float mean = sx * (1.0f / 768.0f);
  float var = fmaxf(sxx * (1.0f / 768.0f) - mean * mean, 0.0f);
  float rs = rsqrtf(var + 1e-5f);
  float* fb = fused + (size_t)b * 1536;
  fb[768 + t] = (v0 - mean) * rs * bn_g[t] + bn_b[t];
  fb[768 + t + 256] = (v1 - mean) * rs * bn_g[t + 256] + bn_b[t + 256];
  fb[768 + t + 512] = (v2 - mean) * rs * bn_g[t + 512] + bn_b[t + 512];
  const float* gr = gf + (size_t)b * 768;
  float g0 = gr[t], g1 = gr[t + 256], g2 = gr[t + 512];
  float gsx = blockReduceSum(g0 + g1 + g2, sh);
  float gsxx = blockReduceSum(g0 * g0 + g1 * g1 + g2 * g2, sh);
  float gm = gsx * (1.0f / 768.0f);
  float gv = fmaxf(gsxx * (1.0f / 768.0f) - gm * gm, 0.0f);
  float grs = rsqrtf(gv + 1e-5f);
  fb[t] = (g0 - gm) * grs * gn_g[t] + gn_b[t];
  fb[t + 256] = (g1 - gm) * grs * gn_g[t + 256] + gn_b[t + 256];
  fb[t + 512] = (g2 - gm) * grs * gn_g[t + 512] + gn_b[t + 512];
}

// ---------------- K14: h = gelu(fused @ hw1 + hb1) — split-K, 4 batches/block ----
__global__ void __launch_bounds__(256) k_head1(
    const float* __restrict__ fused, const float* __restrict__ hw1, const float* __restrict__ hb1,
    float* __restrict__ h) {
  __shared__ float fl[4][1536];
  __shared__ float part[4][4][64];
  int bp = blockIdx.y * 4, h0 = blockIdx.x * 64, t = threadIdx.x;
  for (int i = t; i < 1536; i += 256) {
#pragma unroll
    for (int j = 0; j < 4; j++) fl[j][i] = fused[(size_t)(bp + j) * 1536 + i];
  }
  __syncthreads();
  int c = t & 63, sl = t >> 6;
  int hh = h0 + c;
  int kbase = sl * 384;
  const float* wp = hw1 + (size_t)kbase * 3072 + hh;
  float a0 = 0.f, a1 = 0.f, a2 = 0.f, a3 = 0.f;
#pragma unroll 8
  for (int k = 0; k < 384; k++) {
    float w = wp[(size_t)k * 3072];
    a0 = fmaf(fl[0][kbase + k], w, a0);
    a1 = fmaf(fl[1][kbase + k], w, a1);
    a2 = fmaf(fl[2][kbase + k], w, a2);
    a3 = fmaf(fl[3][kbase + k], w, a3);
  }
  part[0][sl][c] = a0; part[1][sl][c] = a1; part[2][sl][c] = a2; part[3][sl][c] = a3;
  __syncthreads();
  if (sl == 0) {
    float bias = hb1[hh];
#pragma unroll
    for (int j = 0; j < 4; j++) {
      float s = part[j][0][c] + part[j][1][c] + part[j][2][c] + part[j][3][c];
      h[(size_t)(bp + j) * 3072 + hh] = gelu_exact(s + bias);
    }
  }
}

// ---------------- K15: residual/final logits — split-K, 2 batches/block ----------
__global__ void __launch_bounds__(256) k_head2(
    const float* __restrict__ h, const float* __restrict__ hw2, const float* __restrict__ hb2,
    const float* __restrict__ base, float* __restrict__ out) {
  __shared__ float hl[2][3072];
  __shared__ float part[2][4][64];
  int bp = blockIdx.y * 2, c0 = blockIdx.x * 64, t = threadIdx.x;
  for (int i = t; i < 3072; i += 256) {
    hl[0][i] = h[(size_t)bp * 3072 + i];
    hl[1][i] = h[(size_t)(bp + 1) * 3072 + i];
  }
  __syncthreads();
  int c = t & 63, sl = t >> 6;
  int cc = c0 + c;
  int csafe = cc < 1000 ? cc : 999;
  int kbase = sl * 768;
  const float* wp = hw2 + (size_t)kbase * 1000 + csafe;
  float a0 = 0.f, a1 = 0.f;
#pragma unroll 8
  for (int k = 0; k < 768; k++) {
    float w = wp[(size_t)k * 1000];
    a0 = fmaf(hl[0][kbase + k], w, a0);
    a1 = fmaf(hl[1][kbase + k], w, a1);
  }
  part[0][sl][c] = a0; part[1][sl][c] = a1;
  __syncthreads();
  if (sl == 0 && cc < 1000) {
    float bias = hb2[cc];
    float s0 = part[0][0][c] + part[0][1][c] + part[0][2][c] + part[0][3][c] + bias;
    float s1_ = part[1][0][c] + part[1][1][c] + part[1][2][c] + part[1][3][c] + bias;
    out[32000 + bp * 1000 + cc] = s0;
    out[bp * 1000 + cc] = base[bp * 1000 + cc] + s0;
    out[32000 + (bp + 1) * 1000 + cc] = s1_;
    out[(bp + 1) * 1000 + cc] = base[(bp + 1) * 1000 + cc] + s1_;
  }
}

// ---------------- K16: sparse_loss + diversity_loss ----------------
__global__ void __launch_bounds__(256) k_losses(
    const float* __restrict__ scores_raw, const float* __restrict__ rb2,
    const float* __restrict__ gpart, float* __restrict__ out) {
  __shared__ float sh[8];
  int t = threadIdx.x;
  float s = 0.0f;
#pragma unroll
  for (int i = 0; i < 8; i++) {
    float z = scores_raw[t + i * 256] + rb2[0];
    s += fmaxf(z, 0.0f) + log1pf(expf(-fabsf(z)));
  }
  s = blockReduceSum(s, sh);
  float gsum = (t < 64) ? gpart[t] : 0.0f;
  gsum = blockReduceSum(gsum, sh);
  if (t == 0) {
    out[66048] = s * (1.0f / 2048.0f);
    out[66049] = gsum * (1.0f / 4096.0f);
  }
}

// ---------------- launch ----------------
extern "C" void kernel_launch(void* const* d_in, const int* in_sizes, int n_in,
                              void* d_out, int out_size, void* d_ws, size_t ws_size,
                              hipStream_t stream) {
  const float* patch = (const float*)d_in[0];
  const float* gfeat = (const float*)d_in[1];
  const float* base  = (const float*)d_in[2];
  const float* bq    = (const float*)d_in[3];
  const float* qn_g  = (const float*)d_in[4];
  const float* qn_b  = (const float*)d_in[5];
  const float* tn_g  = (const float*)d_in[6];
  const float* tn_b  = (const float*)d_in[7];
  const float* bn_g  = (const float*)d_in[8];
  const float* bn_b  = (const float*)d_in[9];
  const float* gn_g  = (const float*)d_in[10];
  const float* gn_b  = (const float*)d_in[11];
  const float* rln_g = (const float*)d_in[12];
  const float* rln_b = (const float*)d_in[13];
  const float* rw1   = (const float*)d_in[14];
  const float* rb1   = (const float*)d_in[15];
  const float* rw2   = (const float*)d_in[16];
  const float* rb2   = (const float*)d_in[17];
  const float* hw1   = (const float*)d_in[18];
  const float* hb1   = (const float*)d_in[19];
  const float* hw2   = (const float*)d_in[20];
  const float* hb2   = (const float*)d_in[21];
  float* ws = (float*)d_ws;
  float* out = (float*)d_out;

  // workspace layout (f32 offsets); total 14143712 f32 = 56.6 MB
  float* s1      = ws + 0;         // 64
  float* qb      = ws + 64;        // 64
  float* gcons   = ws + 128;       // 32
  float* gpart   = ws + 160;       // 64
  float* fusedb  = ws + 224;       // 49152
  float* hbuf    = ws + 49376;     // 98304
  float* bqn     = ws + 147680;    // 49152
  us*    qgh     = (us*)(ws + 196832);   // 49152 us
  us*    qgl     = (us*)(ws + 221408);   // 49152 us
  us*    w1th    = (us*)(ws + 245984);   // 2359296 us
  us*    w1tl    = (us*)(ws + 1425632);  // 2359296 us
  us*    rhh     = (us*)(ws + 2605280);  // 1572864 us
  us*    rhl     = (us*)(ws + 3391712);  // 1572864 us
  float* bs      = ws + 4178144;   // 1572864  -- [bs|scores|rowsum] zeroed jointly
  float* scores  = ws + 5751008;   // 2048
  float* rowsum  = ws + 5753056;   // 2048
  float* L       = ws + 5755104;   // 8388608 (32*64*4096 f32)

  k_prep_queries<<<dim3(64), 256, 0, stream>>>(bq, qn_g, qn_b, tn_g, tn_b,
                                               qgh, qgl, s1, qb, bqn, gcons);
  k_gram<<<dim3(64), 256, 0, stream>>>(bqn, gpart);
  k_w1t<<<dim3(24, 96), 256, 0, stream>>>(rw1, w1th, w1tl);
  k_zero<<<dim3(1540), 256, 0, stream>>>(bs);  // bs + scores + rowsum
  k_attn_mfma<<<dim3(32, 32), 256, 0, stream>>>(patch, qgh, qgl, s1, qb, tn_g, tn_b,
                                                gcons, L, rowsum);
  k_pv_mfma<<<dim3(6, 32, 8), 256, 0, stream>>>(patch, L, rowsum, bs);
  k_ln768<<<dim3(512), 256, 0, stream>>>(bs, rln_g, rln_b, rhh, rhl);
  k_rh_mfma<<<dim3(24, 16), 512, 0, stream>>>(rhh, rhl, w1th, w1tl, rb1, rw2, scores);
  k_fused<<<dim3(32), 256, 0, stream>>>(bs, scores, rb2, gfeat, bn_g, bn_b, gn_g, gn_b,
                                        fusedb, out + 64000);
  k_head1<<<dim3(48, 8), 256, 0, stream>>>(fusedb, hw1, hb1, hbuf);
  k_head2<<<dim3(16, 16), 256, 0, stream>>>(hbuf, hw2, hb2, base, out);
  k_losses<<<dim3(1), 256, 0, stream>>>(scores, rb2, gpart, out);
}

// Round 13
// 421.401 us; speedup vs baseline: 1.0170x; 1.0170x over previous
//
#include <hip/hip_runtime.h>
#include <math.h>

#define SCALE 0.036084391824351613f /* 1/sqrt(768) */

typedef unsigned short us;
typedef __attribute__((ext_vector_type(8))) short short8;
typedef __attribute__((ext_vector_type(4))) short short4s;
typedef __attribute__((ext_vector_type(4))) float f32x4;
#define MFMA16(a, b, c) __builtin_amdgcn_mfma_f32_16x16x32_bf16(a, b, c, 0, 0, 0)

__device__ __forceinline__ us f2bf(float f) {
  unsigned u = __float_as_uint(f);
  unsigned r = (u + 0x7fffu + ((u >> 16) & 1u)) >> 16;
  return (us)r;
}
__device__ __forceinline__ float bf2f(us u) { return __uint_as_float(((unsigned)u) << 16); }

__device__ __forceinline__ void split8(f32x4 a, f32x4 b, short8& hi, short8& lo) {
  float x[8] = {a[0], a[1], a[2], a[3], b[0], b[1], b[2], b[3]};
#pragma unroll
  for (int i = 0; i < 8; i++) {
    us h = f2bf(x[i]);
    hi[i] = (short)h;
    lo[i] = (short)f2bf(x[i] - bf2f(h));
  }
}

// ---------------- reduction helpers (blockDim = 256) ----------------
__device__ __forceinline__ float blockReduceSum(float v, float* sh) {
#pragma unroll
  for (int o = 32; o > 0; o >>= 1) v += __shfl_xor(v, o, 64);
  int lane = threadIdx.x & 63, wid = threadIdx.x >> 6;
  __syncthreads();
  if (lane == 0) sh[wid] = v;
  __syncthreads();
  float r = sh[0];
  int nw = blockDim.x >> 6;
  for (int i = 1; i < nw; i++) r += sh[i];
  return r;
}

__device__ __forceinline__ float gelu_exact(float x) {
  return 0.5f * x * (1.0f + erff(x * 0.7071067811865476f));
}

// ---------------- K2: queries prep -> qgh/qgl (bf16 hi/lo), s1, qb, bqn, gcons ----
__global__ void __launch_bounds__(256) k_prep_queries(
    const float* __restrict__ bq, const float* __restrict__ qn_g, const float* __restrict__ qn_b,
    const float* __restrict__ tn_g, const float* __restrict__ tn_b,
    us* __restrict__ qgh, us* __restrict__ qgl,
    float* __restrict__ s1, float* __restrict__ qb,
    float* __restrict__ bqn, float* __restrict__ gcons) {
  __shared__ float sh[8];
  int k = blockIdx.x, t = threadIdx.x;
  const float* xr = bq + (size_t)k * 768;
  float x0 = xr[t], x1 = xr[t + 256], x2 = xr[t + 512];
  float sx = blockReduceSum(x0 + x1 + x2, sh);
  float sxx = blockReduceSum(x0 * x0 + x1 * x1 + x2 * x2, sh);
  float mean = sx * (1.0f / 768.0f);
  float var = fmaxf(sxx * (1.0f / 768.0f) - mean * mean, 0.0f);
  float rs = rsqrtf(var + 1e-5f);
  float y0 = (x0 - mean) * rs * qn_g[t] + qn_b[t];
  float y1 = (x1 - mean) * rs * qn_g[t + 256] + qn_b[t + 256];
  float y2 = (x2 - mean) * rs * qn_g[t + 512] + qn_b[t + 512];
  float ss = blockReduceSum(y0 * y0 + y1 * y1 + y2 * y2, sh);
  float inv = 1.0f / fmaxf(sqrtf(ss), 1e-12f);
  float q0 = y0 * inv, q1 = y1 * inv, q2 = y2 * inv;
  float tg0 = tn_g[t], tg1 = tn_g[t + 256], tg2 = tn_g[t + 512];
  float tb0 = tn_b[t], tb1 = tn_b[t + 256], tb2 = tn_b[t + 512];
  float g0 = q0 * tg0, g1 = q1 * tg1, g2 = q2 * tg2;
  us h0 = f2bf(g0), h1 = f2bf(g1), h2 = f2bf(g2);
  qgh[(size_t)k * 768 + t] = h0;
  qgh[(size_t)k * 768 + t + 256] = h1;
  qgh[(size_t)k * 768 + t + 512] = h2;
  qgl[(size_t)k * 768 + t] = f2bf(g0 - bf2f(h0));
  qgl[(size_t)k * 768 + t + 256] = f2bf(g1 - bf2f(h1));
  qgl[(size_t)k * 768 + t + 512] = f2bf(g2 - bf2f(h2));
  float s1p = blockReduceSum(g0 + g1 + g2, sh);
  float qbp = blockReduceSum(q0 * tb0 + q1 * tb1 + q2 * tb2, sh);
  if (t == 0) { s1[k] = s1p; qb[k] = qbp; }
  float inv2 = 1.0f / fmaxf(sqrtf(sxx), 1e-12f);
  bqn[(size_t)k * 768 + t] = x0 * inv2;
  bqn[(size_t)k * 768 + t + 256] = x1 * inv2;
  bqn[(size_t)k * 768 + t + 512] = x2 * inv2;
  float sggp = blockReduceSum(tg0 * tg0 + tg1 * tg1 + tg2 * tg2, sh);
  float sgbp = blockReduceSum(tg0 * tb0 + tg1 * tb1 + tg2 * tb2, sh);
  float sbbp = blockReduceSum(tb0 * tb0 + tb1 * tb1 + tb2 * tb2, sh);
  if (k == 0 && t == 0) { gcons[0] = sggp; gcons[1] = sgbp; gcons[2] = sbbp; }
}

// ---------------- K3: gram row-k squared error partials ----------------
__global__ void __launch_bounds__(256) k_gram(const float* __restrict__ bqn,
                                              float* __restrict__ gpart) {
  __shared__ float bk[768];
  __shared__ float arr[64];
  int k = blockIdx.x, t = threadIdx.x;
  bk[t] = bqn[(size_t)k * 768 + t];
  bk[t + 256] = bqn[(size_t)k * 768 + t + 256];
  bk[t + 512] = bqn[(size_t)k * 768 + t + 512];
  __syncthreads();
  int j = t >> 2, sub = t & 3;
  const float* bj = bqn + (size_t)j * 768 + sub * 192;
  float v = 0.0f;
  for (int d = 0; d < 192; d++) v += bk[sub * 192 + d] * bj[d];
  v += __shfl_xor(v, 1, 64);
  v += __shfl_xor(v, 2, 64);
  if (sub == 0) { float e = v - (j == k ? 1.0f : 0.0f); arr[j] = e * e; }
  __syncthreads();
  if (t < 64) {
    float s = arr[t];
#pragma unroll
    for (int o = 32; o > 0; o >>= 1) s += __shfl_xor(s, o, 64);
    if (t == 0) gpart[k] = s;
  }
}

// ---------------- K4: transpose+split rw1 [768,3072] -> w1th/w1tl [3072,768] -----
__global__ void __launch_bounds__(256) k_w1t(const float* __restrict__ rw1,
                                             us* __restrict__ w1th, us* __restrict__ w1tl) {
  __shared__ float tl[32][33];
  int d0 = blockIdx.x * 32, h0 = blockIdx.y * 32;
  int t = threadIdx.x, tx = t & 31, ty = t >> 5;
#pragma unroll
  for (int j = 0; j < 4; j++)
    tl[ty + j * 8][tx] = rw1[(size_t)(d0 + ty + j * 8) * 3072 + h0 + tx];
  __syncthreads();
#pragma unroll
  for (int j = 0; j < 4; j++) {
    float v = tl[tx][ty + j * 8];
    us h = f2bf(v);
    w1th[(size_t)(h0 + ty + j * 8) * 768 + d0 + tx] = h;
    w1tl[(size_t)(h0 + ty + j * 8) * 768 + d0 + tx] = f2bf(v - bf2f(h));
  }
}

// ---------------- K5: attn logits GEMM + fused LN/L2 stats; stores exp(v) f32 ----
__global__ void __launch_bounds__(256) k_attn_mfma(
    const float* __restrict__ x, const us* __restrict__ qgh, const us* __restrict__ qgl,
    const float* __restrict__ s1v, const float* __restrict__ qbv,
    const float* __restrict__ tng, const float* __restrict__ tnb,
    const float* __restrict__ gcons, float* __restrict__ E, float* __restrict__ rowsum) {
  __shared__ __align__(16) us qsh[64 * 32], qsl[64 * 32];
  __shared__ __align__(16) us xsh[128 * 32], xsl[128 * 32];
  __shared__ float sA[128], sB[128], sC[128];
  __shared__ float sRow[4][64];
  const int b = blockIdx.y, n0 = blockIdx.x * 128;
  const int t = threadIdx.x, w = t >> 6, l = t & 63;
  const int sr = t >> 2, sq = t & 3;
  const us* qsrcH = qgh + (size_t)sr * 768 + sq * 8;
  const us* qsrcL = qgl + (size_t)sr * 768 + sq * 8;
  const float* xsrc = x + ((size_t)b * 4096 + n0 + sr) * 768 + sq * 8;
  f32x4 acc[4][2];
#pragma unroll
  for (int i = 0; i < 4; i++)
#pragma unroll
    for (int j = 0; j < 2; j++) acc[i][j] = (f32x4){0.f, 0.f, 0.f, 0.f};
  float s0x = 0, s0xx = 0, s0a = 0, s0b = 0, s0c = 0;
  float t1x = 0, t1xx = 0, t1a = 0, t1b = 0, t1c = 0;
  short8 qh = *(const short8*)qsrcH, ql = *(const short8*)qsrcL;
  f32x4 x0a = *(const f32x4*)xsrc, x0b = *(const f32x4*)(xsrc + 4);
  f32x4 x1a = *(const f32x4*)(xsrc + (size_t)64 * 768);
  f32x4 x1b = *(const f32x4*)(xsrc + (size_t)64 * 768 + 4);
  for (int dk = 0; dk < 768; dk += 32) {
    f32x4 ga = *(const f32x4*)(tng + dk + sq * 8);
    f32x4 gA = *(const f32x4*)(tng + dk + sq * 8 + 4);
    f32x4 ba = *(const f32x4*)(tnb + dk + sq * 8);
    f32x4 bA = *(const f32x4*)(tnb + dk + sq * 8 + 4);
#pragma unroll
    for (int i = 0; i < 4; i++) {
      float g1 = ga[i], g2 = gA[i], b1 = ba[i], b2 = bA[i];
      float xv = x0a[i]; float gx = g1 * xv;
      s0x += xv; s0xx = fmaf(xv, xv, s0xx);
      s0a = fmaf(gx, gx, s0a); s0b = fmaf(g1, gx, s0b); s0c = fmaf(b1, gx, s0c);
      xv = x0b[i]; gx = g2 * xv;
      s0x += xv; s0xx = fmaf(xv, xv, s0xx);
      s0a = fmaf(gx, gx, s0a); s0b = fmaf(g2, gx, s0b); s0c = fmaf(b2, gx, s0c);
      xv = x1a[i]; gx = g1 * xv;
      t1x += xv; t1xx = fmaf(xv, xv, t1xx);
      t1a = fmaf(gx, gx, t1a); t1b = fmaf(g1, gx, t1b); t1c = fmaf(b1, gx, t1c);
      xv = x1b[i]; gx = g2 * xv;
      t1x += xv; t1xx = fmaf(xv, xv, t1xx);
      t1a = fmaf(gx, gx, t1a); t1b = fmaf(g2, gx, t1b); t1c = fmaf(b2, gx, t1c);
    }
    short8 hi, lo;
    __syncthreads();
    *(short8*)&qsh[sr * 32 + sq * 8] = qh; *(short8*)&qsl[sr * 32 + sq * 8] = ql;
    split8(x0a, x0b, hi, lo);
    *(short8*)&xsh[sr * 32 + sq * 8] = hi; *(short8*)&xsl[sr * 32 + sq * 8] = lo;
    split8(x1a, x1b, hi, lo);
    *(short8*)&xsh[(sr + 64) * 32 + sq * 8] = hi; *(short8*)&xsl[(sr + 64) * 32 + sq * 8] = lo;
    __syncthreads();
    if (dk + 32 < 768) {
      int d2 = dk + 32;
      qh = *(const short8*)(qsrcH + d2); ql = *(const short8*)(qsrcL + d2);
      x0a = *(const f32x4*)(xsrc + d2); x0b = *(const f32x4*)(xsrc + d2 + 4);
      x1a = *(const f32x4*)(xsrc + (size_t)64 * 768 + d2);
      x1b = *(const f32x4*)(xsrc + (size_t)64 * 768 + d2 + 4);
    }
    short8 ah[4], al[4];
#pragma unroll
    for (int kt = 0; kt < 4; kt++) {
      int off = (kt * 16 + (l & 15)) * 32 + (l >> 4) * 8;
      ah[kt] = *(const short8*)&qsh[off];
      al[kt] = *(const short8*)&qsl[off];
    }
#pragma unroll
    for (int nt = 0; nt < 2; nt++) {
      int off = (w * 32 + nt * 16 + (l & 15)) * 32 + (l >> 4) * 8;
      short8 bh = *(const short8*)&xsh[off];
      short8 bl = *(const short8*)&xsl[off];
#pragma unroll
      for (int kt = 0; kt < 4; kt++) {
        acc[kt][nt] = MFMA16(ah[kt], bh, acc[kt][nt]);
        acc[kt][nt] = MFMA16(ah[kt], bl, acc[kt][nt]);
        acc[kt][nt] = MFMA16(al[kt], bh, acc[kt][nt]);
        acc[kt][nt] = MFMA16(al[kt], bl, acc[kt][nt]);
      }
    }
  }
  float sgg = gcons[0], sgb = gcons[1], sbb = gcons[2];
#define R4(v) v += __shfl_xor(v, 1, 64); v += __shfl_xor(v, 2, 64)
  R4(s0x); R4(s0xx); R4(s0a); R4(s0b); R4(s0c);
  R4(t1x); R4(t1xx); R4(t1a); R4(t1b); R4(t1c);
#undef R4
  if (sq == 0) {
    {
      float m = s0x * (1.0f / 768.0f);
      float var = fmaxf(s0xx * (1.0f / 768.0f) - m * m, 0.0f);
      float rs = rsqrtf(var + 1e-5f);
      float ss = fmaxf(rs * rs * (s0a - 2.0f * m * s0b + m * m * sgg) +
                       2.0f * rs * (s0c - m * sgb) + sbb, 0.0f);
      float inv = 1.0f / fmaxf(sqrtf(ss), 1e-12f);
      float A = SCALE * inv * rs;
      sA[sr] = A; sB[sr] = A * m; sC[sr] = SCALE * inv;
    }
    {
      float m = t1x * (1.0f / 768.0f);
      float var = fmaxf(t1xx * (1.0f / 768.0f) - m * m, 0.0f);
      float rs = rsqrtf(var + 1e-5f);
      float ss = fmaxf(rs * rs * (t1a - 2.0f * m * t1b + m * m * sgg) +
                       2.0f * rs * (t1c - m * sgb) + sbb, 0.0f);
      float inv = 1.0f / fmaxf(sqrtf(ss), 1e-12f);
      float A = SCALE * inv * rs;
      sA[sr + 64] = A; sB[sr + 64] = A * m; sC[sr + 64] = SCALE * inv;
    }
  }
  __syncthreads();
  // |logit| <= SCALE (unit-vector dot) -> exp without max-subtraction is safe.
  // Store e = exp(v) directly (bit-identical to recomputing exp in pv).
  float esum[4][4];
#pragma unroll
  for (int kt = 0; kt < 4; kt++)
#pragma unroll
    for (int r = 0; r < 4; r++) esum[kt][r] = 0.f;
#pragma unroll
  for (int nt = 0; nt < 2; nt++) {
    int nn = w * 32 + nt * 16 + (l & 15);
    int n = n0 + nn;
    float Av = sA[nn], Bv = sB[nn], Cv = sC[nn];
#pragma unroll
    for (int kt = 0; kt < 4; kt++) {
#pragma unroll
      for (int r = 0; r < 4; r++) {
        int k = kt * 16 + (l >> 4) * 4 + r;
        float v = Av * acc[kt][nt][r] - Bv * s1v[k] + Cv * qbv[k];
        float e = expf(v);
        E[((size_t)b * 64 + k) * 4096 + n] = e;
        esum[kt][r] += e;
      }
    }
  }
#pragma unroll
  for (int kt = 0; kt < 4; kt++)
#pragma unroll
    for (int r = 0; r < 4; r++) {
      float e = esum[kt][r];
      e += __shfl_xor(e, 1, 64);
      e += __shfl_xor(e, 2, 64);
      e += __shfl_xor(e, 4, 64);
      e += __shfl_xor(e, 8, 64);
      if ((l & 15) == 0) sRow[w][kt * 16 + (l >> 4) * 4 + r] = e;
    }
  __syncthreads();
  if (t < 64)
    atomicAdd(&rowsum[b * 64 + t], sRow[0][t] + sRow[1][t] + sRow[2][t] + sRow[3][t]);
}

// ---------------- K7: zero bs + scores + rowsum (contiguous) ----------------
__global__ void __launch_bounds__(256) k_zero(float* __restrict__ p) {
  ((f32x4*)p)[blockIdx.x * 256 + threadIdx.x] = (f32x4){0.f, 0.f, 0.f, 0.f};
}

// ---------------- K8: basis_states GEMM (d=128, z=8); W = stored exp * 1/rowsum --
__global__ void __launch_bounds__(256) k_pv_mfma(
    const float* __restrict__ x, const float* __restrict__ E,
    const float* __restrict__ rowsum, float* __restrict__ S) {
  __shared__ __align__(16) us wth[64 * 32], wtl[64 * 32];
  __shared__ __align__(16) us xth[8 * 32 * 16], xtl[8 * 32 * 16];
  const int b = blockIdx.y, d0 = blockIdx.x * 128, nb = blockIdx.z * 512;
  const int t = threadIdx.x, w = t >> 6, l = t & 63;
  const int krow = t >> 2;
  const float* wsrc = E + ((size_t)b * 64 + krow) * 4096 + nb + (t & 3) * 8;
  const float ir = 1.0f / rowsum[b * 64 + krow];
  const int gg = t >> 6, nn = (t >> 1) & 31, hh = t & 1;
  const float* xsrc0 = x + ((size_t)b * 4096 + nb + nn) * 768 + d0 + gg * 16 + hh * 8;
  const float* xsrc1 = xsrc0 + 64;  // groups 4..7
  f32x4 acc[4][2];
#pragma unroll
  for (int i = 0; i < 4; i++)
#pragma unroll
    for (int j = 0; j < 2; j++) acc[i][j] = (f32x4){0.f, 0.f, 0.f, 0.f};
  f32x4 w0a = *(const f32x4*)wsrc, w0b = *(const f32x4*)(wsrc + 4);
  f32x4 xa0 = *(const f32x4*)xsrc0, xb0 = *(const f32x4*)(xsrc0 + 4);
  f32x4 xa1 = *(const f32x4*)xsrc1, xb1 = *(const f32x4*)(xsrc1 + 4);
  for (int ns = 0; ns < 512; ns += 32) {
    short8 hi, lo;
    f32x4 e0, e1;
#pragma unroll
    for (int i = 0; i < 4; i++) {
      e0[i] = w0a[i] * ir;
      e1[i] = w0b[i] * ir;
    }
    __syncthreads();
    split8(e0, e1, hi, lo);
    *(short8*)&wth[krow * 32 + (t & 3) * 8] = hi;
    *(short8*)&wtl[krow * 32 + (t & 3) * 8] = lo;
    split8(xa0, xb0, hi, lo);
    *(short8*)&xth[(size_t)t * 8] = hi; *(short8*)&xtl[(size_t)t * 8] = lo;
    split8(xa1, xb1, hi, lo);
    *(short8*)&xth[((size_t)t + 256) * 8] = hi; *(short8*)&xtl[((size_t)t + 256) * 8] = lo;
    __syncthreads();
    if (ns + 32 < 512) {
      w0a = *(const f32x4*)(wsrc + ns + 32); w0b = *(const f32x4*)(wsrc + ns + 36);
      const float* p0 = xsrc0 + (size_t)(ns + 32) * 768;
      xa0 = *(const f32x4*)p0; xb0 = *(const f32x4*)(p0 + 4);
      xa1 = *(const f32x4*)(p0 + 64); xb1 = *(const f32x4*)(p0 + 68);
    }
    short8 ah[4], al[4];
#pragma unroll
    for (int kt = 0; kt < 4; kt++) {
      int off = (kt * 16 + (l & 15)) * 32 + (l >> 4) * 8;
      ah[kt] = *(const short8*)&wth[off];
      al[kt] = *(const short8*)&wtl[off];
    }
#pragma unroll
    for (int dt = 0; dt < 2; dt++) {
      const us* gph = &xth[(2 * w + dt) * 512];
      const us* gpl = &xtl[(2 * w + dt) * 512];
      int rb = (l >> 4) * 8, cc = l & 15;
      short8 bh, bl;
#pragma unroll
      for (int i = 0; i < 8; i++) {
        bh[i] = (short)gph[(rb + i) * 16 + cc];
        bl[i] = (short)gpl[(rb + i) * 16 + cc];
      }
#pragma unroll
      for (int kt = 0; kt < 4; kt++) {
        acc[kt][dt] = MFMA16(ah[kt], bh, acc[kt][dt]);
        acc[kt][dt] = MFMA16(ah[kt], bl, acc[kt][dt]);
        acc[kt][dt] = MFMA16(al[kt], bh, acc[kt][dt]);
        acc[kt][dt] = MFMA16(al[kt], bl, acc[kt][dt]);
      }
    }
  }
#pragma unroll
  for (int dt = 0; dt < 2; dt++) {
    int d = d0 + w * 32 + dt * 16 + (l & 15);
#pragma unroll
    for (int kt = 0; kt < 4; kt++) {
#pragma unroll
      for (int r = 0; r < 4; r++) {
        int k = kt * 16 + (l >> 4) * 4 + r;
        atomicAdd(&S[((size_t)b * 64 + k) * 768 + d], acc[kt][dt][r]);
      }
    }
  }
}

// ---------------- K9: LN over 768 rows -> bf16 hi/lo out (wave-per-row) ---------
__global__ void __launch_bounds__(256) k_ln768(
    const float* __restrict__ in, const float* __restrict__ g, const float* __restrict__ b,
    us* __restrict__ outh, us* __restrict__ outl) {
  int wid = threadIdx.x >> 6, lane = threadIdx.x & 63;
  size_t row = (size_t)blockIdx.x * 4 + wid;
  const f32x4* xr = (const f32x4*)(in + row * 768);
  f32x4 v[3];
  float sx = 0, sxx = 0;
#pragma unroll
  for (int j = 0; j < 3; j++) {
    v[j] = xr[lane + j * 64];
#pragma unroll
    for (int i = 0; i < 4; i++) { sx += v[j][i]; sxx = fmaf(v[j][i], v[j][i], sxx); }
  }
#pragma unroll
  for (int o = 32; o > 0; o >>= 1) { sx += __shfl_xor(sx, o, 64); sxx += __shfl_xor(sxx, o, 64); }
  float mean = sx * (1.0f / 768.0f);
  float var = fmaxf(sxx * (1.0f / 768.0f) - mean * mean, 0.0f);
  float rs = rsqrtf(var + 1e-5f);
  const f32x4* gp = (const f32x4*)g;
  const f32x4* bp = (const f32x4*)b;
#pragma unroll
  for (int j = 0; j < 3; j++) {
    f32x4 gv = gp[lane + j * 64], bv = bp[lane + j * 64];
    short4s h4, l4;
#pragma unroll
    for (int i = 0; i < 4; i++) {
      float y = (v[j][i] - mean) * rs * gv[i] + bv[i];
      us h = f2bf(y);
      h4[i] = (short)h;
      l4[i] = (short)f2bf(y - bf2f(h));
    }
    int e = (lane + j * 64) * 4;
    *(short4s*)&outh[row * 768 + e] = h4;
    *(short4s*)&outl[row * 768 + e] = l4;
  }
}

// ---------------- K10: routing-MLP GEMM 128x128, 512 thr, fused score dot -------
__global__ void __launch_bounds__(512) k_rh_mfma(
    const us* __restrict__ rhh, const us* __restrict__ rhl,
    const us* __restrict__ w1th, const us* __restrict__ w1tl,
    const float* __restrict__ rb1, const float* __restrict__ rw2,
    float* __restrict__ scores_raw) {
  __shared__ __align__(16) us ash[128 * 32], asl[128 * 32];
  __shared__ __align__(16) us bsh[128 * 32], bsl[128 * 32];
  __shared__ float spart[4][128];
  const int h0 = blockIdx.x * 128, m0 = blockIdx.y * 128;
  const int t = threadIdx.x, w = t >> 6, l = t & 63;
  const int wm = w >> 2, wh = w & 3;
  const int sr = t >> 2, sq = t & 3;
  const us* aH = rhh + (size_t)(m0 + sr) * 768 + sq * 8;
  const us* aL = rhl + (size_t)(m0 + sr) * 768 + sq * 8;
  const us* bH = w1th + (size_t)(h0 + sr) * 768 + sq * 8;
  const us* bL = w1tl + (size_t)(h0 + sr) * 768 + sq * 8;
  f32x4 acc[4][2];
#pragma unroll
  for (int i = 0; i < 4; i++)
#pragma unroll
    for (int j = 0; j < 2; j++) acc[i][j] = (f32x4){0.f, 0.f, 0.f, 0.f};
  short8 a0h = *(const short8*)aH, a0l = *(const short8*)aL;
  short8 b0h = *(const short8*)bH, b0l = *(const short8*)bL;
  for (int dk = 0; dk < 768; dk += 32) {
    __syncthreads();
    *(short8*)&ash[sr * 32 + sq * 8] = a0h; *(short8*)&asl[sr * 32 + sq * 8] = a0l;
    *(short8*)&bsh[sr * 32 + sq * 8] = b0h; *(short8*)&bsl[sr * 32 + sq * 8] = b0l;
    __syncthreads();
    if (dk + 32 < 768) {
      int d2 = dk + 32;
      a0h = *(const short8*)(aH + d2); a0l = *(const short8*)(aL + d2);
      b0h = *(const short8*)(bH + d2); b0l = *(const short8*)(bL + d2);
    }
    short8 ah[4], al[4];
#pragma unroll
    for (int kt = 0; kt < 4; kt++) {
      int off = ((wm * 64 + kt * 16 + (l & 15))) * 32 + (l >> 4) * 8;
      ah[kt] = *(const short8*)&ash[off];
      al[kt] = *(const short8*)&asl[off];
    }
#pragma unroll
    for (int nt = 0; nt < 2; nt++) {
      int off = ((wh * 32 + nt * 16 + (l & 15))) * 32 + (l >> 4) * 8;
      short8 bh = *(const short8*)&bsh[off];
      short8 bl = *(const short8*)&bsl[off];
#pragma unroll
      for (int kt = 0; kt < 4; kt++) {
        acc[kt][nt] = MFMA16(ah[kt], bh, acc[kt][nt]);
        acc[kt][nt] = MFMA16(ah[kt], bl, acc[kt][nt]);
        acc[kt][nt] = MFMA16(al[kt], bh, acc[kt][nt]);
        acc[kt][nt] = MFMA16(al[kt], bl, acc[kt][nt]);
      }
    }
  }
  float psum[4][4];
#pragma unroll
  for (int kt = 0; kt < 4; kt++)
#pragma unroll
    for (int r = 0; r < 4; r++) psum[kt][r] = 0.f;
#pragma unroll
  for (int nt = 0; nt < 2; nt++) {
    int h = h0 + wh * 32 + nt * 16 + (l & 15);
    float bias = rb1[h];
    float rw2v = rw2[h];
#pragma unroll
    for (int kt = 0; kt < 4; kt++) {
#pragma unroll
      for (int r = 0; r < 4; r++) {
        float g = gelu_exact(acc[kt][nt][r] + bias);
        psum[kt][r] = fmaf(g, rw2v, psum[kt][r]);
      }
    }
  }
#pragma unroll
  for (int kt = 0; kt < 4; kt++)
#pragma unroll
    for (int r = 0; r < 4; r++) {
      float v = psum[kt][r];
      v += __shfl_xor(v, 1, 64);
      v += __shfl_xor(v, 2, 64);
      v += __shfl_xor(v, 4, 64);
      v += __shfl_xor(v, 8, 64);
      if ((l & 15) == 0) spart[wh][wm * 64 + kt * 16 + (l >> 4) * 4 + r] = v;
    }
  __syncthreads();
  if (t < 128)
    atomicAdd(&scores_raw[m0 + t], spart[0][t] + spart[1][t] + spart[2][t] + spart[3][t]);
}

// ---------------- K13: topk + basis_summary + both LNs -> fused [32,1536] --------
__global__ void __launch_bounds__(256) k_fused(
    const float* __restrict__ bs, const float* __restrict__ scores_raw,
    const float* __restrict__ rb2, const float* __restrict__ gf,
    const float* __restrict__ bn_g, const float* __restrict__ bn_b,
    const float* __restrict__ gn_g, const float* __restrict__ gn_b,
    float* __restrict__ fused, float* __restrict__ rw_out) {
  __shared__ float sh[8];
  __shared__ float wsh[64];
  int b = blockIdx.x, t = threadIdx.x;
  if (t < 64) {
    float z = scores_raw[b * 64 + t] + rb2[0];
    float s = fmaxf(z, 0.0f) + log1pf(expf(-fabsf(z)));
    bool sel = false;
    for (int it = 0; it < 8; it++) {
      float v = sel ? -INFINITY : s;
      int idx = t;
#pragma unroll
      for (int o = 32; o > 0; o >>= 1) {
        float v2 = __shfl_xor(v, o, 64);
        int i2 = __shfl_xor(idx, o, 64);
        if (v2 > v || (v2 == v && i2 < idx)) { v = v2; idx = i2; }
      }
      if (t == idx) sel = true;
    }
    float wv = sel ? s : 0.0f;
    float tot = wv;
#pragma unroll
    for (int o = 32; o > 0; o >>= 1) tot += __shfl_xor(tot, o, 64);
    float wt = wv / fmaxf(tot, 1e-8f);
    wsh[t] = wt;
    rw_out[b * 64 + t] = wt;
  }
  __syncthreads();
  float v0 = 0, v1 = 0, v2 = 0;
  const float* bsb = bs + (size_t)b * 64 * 768;
  for (int k = 0; k < 64; k++) {
    float w = wsh[k];
    if (w != 0.0f) {
      v0 = fmaf(w, bsb[(size_t)k * 768 + t], v0);
      v1 = fmaf(w, bsb[(size_t)k * 768 + t + 256], v1);
      v2 = fmaf(w, bsb[(size_t)k * 768 + t + 512], v2);
    }
  }
  float sx = blockReduceSum(v0 + v1 + v2, sh);
  float sxx = blockReduceSum(v0 * v0 + v1 * v1 + v2 * v2, sh);
  float mean = sx * (1.0f / 768.0f);
  float var = fmaxf(sxx * (1.0f / 768.0f) - mean * mean, 0.0f);
  float rs = rsqrtf(var + 1e-5f);
  float* fb = fused + (size_t)b * 1536;
  fb[768 + t] = (v0 - mean) * rs * bn_g[t] + bn_b[t];
  fb[768 + t + 256] = (v1 - mean) * rs * bn_g[t + 256] + bn_b[t + 256];
  fb[768 + t + 512] = (v2 - mean) * rs * bn_g[t + 512] + bn_b[t + 512];
  const float* gr = gf + (size_t)b * 768;
  float g0 = gr[t], g1 = gr[t + 256], g2 = gr[t + 512];
  float gsx = blockReduceSum(g0 + g1 + g2, sh);
  float gsxx = blockReduceSum(g0 * g0 + g1 * g1 + g2 * g2, sh);
  float gm = gsx * (1.0f / 768.0f);
  float gv = fmaxf(gsxx * (1.0f / 768.0f) - gm * gm, 0.0f);
  float grs = rsqrtf(gv + 1e-5f);
  fb[t] = (g0 - gm) * grs * gn_g[t] + gn_b[t];
  fb[t + 256] = (g1 - gm) * grs * gn_g[t + 256] + gn_b[t + 256];
  fb[t + 512] = (g2 - gm) * grs * gn_g[t + 512] + gn_b[t + 512];
}

// ---------------- K14: h = gelu(fused @ hw1 + hb1) — split-K, 4 batches/block ----
__global__ void __launch_bounds__(256) k_head1(
    const float* __restrict__ fused, const float* __restrict__ hw1, const float* __restrict__ hb1,
    float* __restrict__ h) {
  __shared__ float fl[4][1536];
  __shared__ float part[4][4][64];
  int bp = blockIdx.y * 4, h0 = blockIdx.x * 64, t = threadIdx.x;
  for (int i = t; i < 1536; i += 256) {
#pragma unroll
    for (int j = 0; j < 4; j++) fl[j][i] = fused[(size_t)(bp + j) * 1536 + i];
  }
  __syncthreads();
  int c = t & 63, sl = t >> 6;
  int hh = h0 + c;
  int kbase = sl * 384;
  const float* wp = hw1 + (size_t)kbase * 3072 + hh;
  float a0 = 0.f, a1 = 0.f, a2 = 0.f, a3 = 0.f;
#pragma unroll 8
  for (int k = 0; k < 384; k++) {
    float w = wp[(size_t)k * 3072];
    a0 = fmaf(fl[0][kbase + k], w, a0);
    a1 = fmaf(fl[1][kbase + k], w, a1);
    a2 = fmaf(fl[2][kbase + k], w, a2);
    a3 = fmaf(fl[3][kbase + k], w, a3);
  }
  part[0][sl][c] = a0; part[1][sl][c] = a1; part[2][sl][c] = a2; part[3][sl][c] = a3;
  __syncthreads();
  if (sl == 0) {
    float bias = hb1[hh];
#pragma unroll
    for (int j = 0; j < 4; j++) {
      float s = part[j][0][c] + part[j][1][c] + part[j][2][c] + part[j][3][c];
      h[(size_t)(bp + j) * 3072 + hh] = gelu_exact(s + bias);
    }
  }
}

// ---------------- K15: residual/final logits — split-K, 2 batches/block ----------
__global__ void __launch_bounds__(256) k_head2(
    const float* __restrict__ h, const float* __restrict__ hw2, const float* __restrict__ hb2,
    const float* __restrict__ base, float* __restrict__ out) {
  __shared__ float hl[2][3072];
  __shared__ float part[2][4][64];
  int bp = blockIdx.y * 2, c0 = blockIdx.x * 64, t = threadIdx.x;
  for (int i = t; i < 3072; i += 256) {
    hl[0][i] = h[(size_t)bp * 3072 + i];
    hl[1][i] = h[(size_t)(bp + 1) * 3072 + i];
  }
  __syncthreads();
  int c = t & 63, sl = t >> 6;
  int cc = c0 + c;
  int csafe = cc < 1000 ? cc : 999;
  int kbase = sl * 768;
  const float* wp = hw2 + (size_t)kbase * 1000 + csafe;
  float a0 = 0.f, a1 = 0.f;
#pragma unroll 8
  for (int k = 0; k < 768; k++) {
    float w = wp[(size_t)k * 1000];
    a0 = fmaf(hl[0][kbase + k], w, a0);
    a1 = fmaf(hl[1][kbase + k], w, a1);
  }
  part[0][sl][c] = a0; part[1][sl][c] = a1;
  __syncthreads();
  if (sl == 0 && cc < 1000) {
    float bias = hb2[cc];
    float s0 = part[0][0][c] + part[0][1][c] + part[0][2][c] + part[0][3][c] + bias;
    float s1_ = part[1][0][c] + part[1][1][c] + part[1][2][c] + part[1][3][c] + bias;
    out[32000 + bp * 1000 + cc] = s0;
    out[bp * 1000 + cc] = base[bp * 1000 + cc] + s0;
    out[32000 + (bp + 1) * 1000 + cc] = s1_;
    out[(bp + 1) * 1000 + cc] = base[(bp + 1) * 1000 + cc] + s1_;
  }
}

// ---------------- K16: sparse_loss + diversity_loss ----------------
__global__ void __launch_bounds__(256) k_losses(
    const float* __restrict__ scores_raw, const float* __restrict__ rb2,
    const float* __restrict__ gpart, float* __restrict__ out) {
  __shared__ float sh[8];
  int t = threadIdx.x;
  float s = 0.0f;
#pragma unroll
  for (int i = 0; i < 8; i++) {
    float z = scores_raw[t + i * 256] + rb2[0];
    s += fmaxf(z, 0.0f) + log1pf(expf(-fabsf(z)));
  }
  s = blockReduceSum(s, sh);
  float gsum = (t < 64) ? gpart[t] : 0.0f;
  gsum = blockReduceSum(gsum, sh);
  if (t == 0) {
    out[66048] = s * (1.0f / 2048.0f);
    out[66049] = gsum * (1.0f / 4096.0f);
  }
}

// ---------------- launch ----------------
extern "C" void kernel_launch(void* const* d_in, const int* in_sizes, int n_in,
                              void* d_out, int out_size, void* d_ws, size_t ws_size,
                              hipStream_t stream) {
  const float* patch = (const float*)d_in[0];
  const float* gfeat = (const float*)d_in[1];
  const float* base  = (const float*)d_in[2];
  const float* bq    = (const float*)d_in[3];
  const float* qn_g  = (const float*)d_in[4];
  const float* qn_b  = (const float*)d_in[5];
  const float* tn_g  = (const float*)d_in[6];
  const float* tn_b  = (const float*)d_in[7];
  const float* bn_g  = (const float*)d_in[8];
  const float* bn_b  = (const float*)d_in[9];
  const float* gn_g  = (const float*)d_in[10];
  const float* gn_b  = (const float*)d_in[11];
  const float* rln_g = (const float*)d_in[12];
  const float* rln_b = (const float*)d_in[13];
  const float* rw1   = (const float*)d_in[14];
  const float* rb1   = (const float*)d_in[15];
  const float* rw2   = (const float*)d_in[16];
  const float* rb2   = (const float*)d_in[17];
  const float* hw1   = (const float*)d_in[18];
  const float* hb1   = (const float*)d_in[19];
  const float* hw2   = (const float*)d_in[20];
  const float* hb2   = (const float*)d_in[21];
  float* ws = (float*)d_ws;
  float* out = (float*)d_out;

  // workspace layout (f32 offsets); total 14143712 f32 = 56.6 MB
  float* s1      = ws + 0;         // 64
  float* qb      = ws + 64;        // 64
  float* gcons   = ws + 128;       // 32
  float* gpart   = ws + 160;       // 64
  float* fusedb  = ws + 224;       // 49152
  float* hbuf    = ws + 49376;     // 98304
  float* bqn     = ws + 147680;    // 49152
  us*    qgh     = (us*)(ws + 196832);   // 49152 us
  us*    qgl     = (us*)(ws + 221408);   // 49152 us
  us*    w1th    = (us*)(ws + 245984);   // 2359296 us
  us*    w1tl    = (us*)(ws + 1425632);  // 2359296 us
  us*    rhh     = (us*)(ws + 2605280);  // 1572864 us
  us*    rhl     = (us*)(ws + 3391712);  // 1572864 us
  float* bs      = ws + 4178144;   // 1572864  -- [bs|scores|rowsum] zeroed jointly
  float* scores  = ws + 5751008;   // 2048
  float* rowsum  = ws + 5753056;   // 2048
  float* E       = ws + 5755104;   // 8388608 (32*64*4096 f32, exp(logit))

  k_prep_queries<<<dim3(64), 256, 0, stream>>>(bq, qn_g, qn_b, tn_g, tn_b,
                                               qgh, qgl, s1, qb, bqn, gcons);
  k_gram<<<dim3(64), 256, 0, stream>>>(bqn, gpart);
  k_w1t<<<dim3(24, 96), 256, 0, stream>>>(rw1, w1th, w1tl);
  k_zero<<<dim3(1540), 256, 0, stream>>>(bs);  // bs + scores + rowsum
  k_attn_mfma<<<dim3(32, 32), 256, 0, stream>>>(patch, qgh, qgl, s1, qb, tn_g, tn_b,
                                                gcons, E, rowsum);
  k_pv_mfma<<<dim3(6, 32, 8), 256, 0, stream>>>(patch, E, rowsum, bs);
  k_ln768<<<dim3(512), 256, 0, stream>>>(bs, rln_g, rln_b, rhh, rhl);
  k_rh_mfma<<<dim3(24, 16), 512, 0, stream>>>(rhh, rhl, w1th, w1tl, rb1, rw2, scores);
  k_fused<<<dim3(32), 256, 0, stream>>>(bs, scores, rb2, gfeat, bn_g, bn_b, gn_g, gn_b,
                                        fusedb, out + 64000);
  k_head1<<<dim3(48, 8), 256, 0, stream>>>(fusedb, hw1, hb1, hbuf);
  k_head2<<<dim3(16, 16), 256, 0, stream>>>(hbuf, hw2, hb2, base, out);
  k_losses<<<dim3(1), 256, 0, stream>>>(scores, rb2, gpart, out);
}